// Round 2
// baseline (401.843 us; speedup 1.0000x reference)
//
#include <hip/hip_runtime.h>

#define HH 512
#define WW 512
#define RR 5
#define KS 11
#define EPS_F 1e-5f
#define NLOG2E 1.44269504088896340736f
#define ROWS 8   // output rows per thread (column coarsening)

// Per-thread: 8-row output column. Neighbor window 18 rows x 11 cols is shared
// across the 8 outputs. Per neighbor: 1 exp2 + 6 muls -> axis powers
// t^{m^2}, m=0..5; per (neighbor, out-row) pair: 1 weight mul + 4 FMAs.
template <bool INTERIOR>
__device__ __forceinline__ void col_body(const float* __restrict__ img,
                                         const float* __restrict__ pw,
                                         float* __restrict__ outb,
                                         int x, int y0) {
    float o0[ROWS], o1[ROWS], o2[ROWS], ws[ROWS];
#pragma unroll
    for (int o = 0; o < ROWS; ++o) { o0[o] = o1[o] = o2[o] = 0.0f; ws[o] = 0.0f; }

#pragma unroll
    for (int r = 0; r < ROWS + 2 * RR; ++r) {      // 18 neighbor rows
        const int ny = y0 + r - RR;
        int nyc = ny;
        bool rowin = true;
        if (!INTERIOR) {
            rowin = (unsigned)ny < (unsigned)HH;
            nyc = ny < 0 ? 0 : (ny > HH - 1 ? HH - 1 : ny);
        }
#pragma unroll
        for (int j = 0; j < KS; ++j) {             // 11 neighbor cols
            const int nx = x + j - RR;
            int nxc = nx;
            bool in = true;
            if (!INTERIOR) {
                in = rowin && ((unsigned)nx < (unsigned)WW);
                nxc = nx < 0 ? 0 : (nx > WW - 1 ? WW - 1 : nx);
            }
            const int ni = nyc * WW + nxc;
            const float w   = pw[ni];
            const float i0  = img[ni];
            const float i1  = img[HH * WW + ni];
            const float i2v = img[2 * HH * WW + ni];

            // t = exp(-1/(2w^2+eps)) via exp2; powers t^{m^2} by squaring.
            const float denom = fmaf(2.0f * w, w, EPS_F);
            const float a  = -NLOG2E * __builtin_amdgcn_rcpf(denom);
            const float t  = exp2f(a);
            const float t2 = t * t, t4 = t2 * t2, t8 = t4 * t4;
            const float E1 = t, E4 = t4, E9 = t8 * t, E16 = t8 * t8, E25 = E16 * E9;

            const int jj = (j - RR) * (j - RR);    // compile-time after unroll
            float cj = jj == 0 ? 1.0f : jj == 1 ? E1 : jj == 4 ? E4
                     : jj == 9 ? E9 : jj == 16 ? E16 : E25;
            if (!INTERIOR) cj = in ? cj : 0.0f;    // zero weight outside image

            // out rows with |vertical dist| <= RR:  o in [r-2R, r] ∩ [0, ROWS-1]
            const int olo = (r - 2 * RR) < 0 ? 0 : (r - 2 * RR);
            const int ohi = r < (ROWS - 1) ? r : (ROWS - 1);
#pragma unroll
            for (int o = olo; o <= ohi; ++o) {
                const int iv = r - RR - o;         // compile-time
                const int ii = iv * iv;
                const float wi = ii == 0 ? 1.0f : ii == 1 ? E1 : ii == 4 ? E4
                               : ii == 9 ? E9 : ii == 16 ? E16 : E25;
                const float k = cj * wi;
                ws[o] += k;
                o0[o] = fmaf(i0, k, o0[o]);
                o1[o] = fmaf(i1, k, o1[o]);
                o2[o] = fmaf(i2v, k, o2[o]);
            }
        }
    }

#pragma unroll
    for (int o = 0; o < ROWS; ++o) {
        const float s = ws[o];                      // >= 1 (center tap = 1)
        float inv = __builtin_amdgcn_rcpf(s);
        inv = inv * (2.0f - s * inv);               // Newton: ~1e-7 rel
        const int oi = (y0 + o) * WW + x;
        outb[oi]              = o0[o] * inv;
        outb[HH * WW + oi]    = o1[o] * inv;
        outb[2 * HH * WW + oi] = o2[o] * inv;
    }
}

__global__ __launch_bounds__(256, 2) void gauss_psf_kernel(const float* __restrict__ image,
                                                           const float* __restrict__ psf,
                                                           float* __restrict__ out) {
    const int x  = blockIdx.x * 64 + threadIdx.x;             // blockDim (64,4)
    const int y0 = (blockIdx.y * 4 + threadIdx.y) * ROWS;     // block covers 32 rows
    const int b  = blockIdx.z;

    const float* img  = image + (size_t)b * 3 * HH * WW;
    const float* pw   = psf   + (size_t)b * HH * WW;
    float*       outb = out   + (size_t)b * 3 * HH * WW;

    const int bx0 = blockIdx.x * 64, by0 = blockIdx.y * 32;
    const bool interior = (bx0 >= RR) && (bx0 + 63 < WW - RR) &&
                          (by0 >= RR) && (by0 + 31 < HH - RR);

    if (interior) col_body<true>(img, pw, outb, x, y0);
    else          col_body<false>(img, pw, outb, x, y0);
}

extern "C" void kernel_launch(void* const* d_in, const int* in_sizes, int n_in,
                              void* d_out, int out_size, void* d_ws, size_t ws_size,
                              hipStream_t stream) {
    const float* image = (const float*)d_in[0];
    const float* psf   = (const float*)d_in[1];
    float* out = (float*)d_out;

    dim3 block(64, 4, 1);
    dim3 grid(WW / 64, HH / 32, 4);   // 8 x 16 x 4 = 512 blocks, 2048 waves
    gauss_psf_kernel<<<grid, block, 0, stream>>>(image, psf, out);
}